// Round 7
// baseline (151.899 us; speedup 1.0000x reference)
//
#include <hip/hip_runtime.h>
#include <hip/hip_bf16.h>

#define SEQ 4096
#define HID 768
#define NHEAD 12
#define HDIM 64
#define KVB 64
#define NT (SEQ / KVB)   // 64
#define PBK 64
#define PNT (HID / PBK)  // 12

typedef __attribute__((ext_vector_type(8))) short bf16x8;
typedef __attribute__((ext_vector_type(4))) float f32x4;
typedef __attribute__((ext_vector_type(4))) short s16x4;

static __device__ __forceinline__ short f2bf(float f) {
    unsigned u = __builtin_bit_cast(unsigned, f);
    unsigned r = (u + 0x7fffu + ((u >> 16) & 1u)) >> 16;
    return (short)r;
}
static __device__ __forceinline__ float bf2f(unsigned short u) {
    return __builtin_bit_cast(float, (unsigned)u << 16);
}
static __device__ __forceinline__ unsigned cvtpk(float lo, float hi) {
    unsigned r;
    asm("v_cvt_pk_bf16_f32 %0, %1, %2" : "=v"(r) : "v"(lo), "v"(hi));
    return r;
}
static __device__ __forceinline__ float max3f(float a, float b, float c) {
    float r;
    asm("v_max3_f32 %0, %1, %2, %3" : "=v"(r) : "v"(a), "v"(b), "v"(c));
    return r;
}
static __device__ __forceinline__ void glds16(const void* g, void* l) {
    __builtin_amdgcn_global_load_lds(
        (const __attribute__((address_space(1))) unsigned*)g,
        (__attribute__((address_space(3))) unsigned*)l, 16, 0, 0);
}

// ---------------------------------------------------------------------------
// fp32 -> bf16 casts
// ---------------------------------------------------------------------------
__global__ __launch_bounds__(256) void cast_bf16_kernel(
    const float* __restrict__ src, short* __restrict__ dst)
{
    const size_t i = (size_t)blockIdx.x * 256 + threadIdx.x;
    const float4* s = reinterpret_cast<const float4*>(src) + i * 2;
    const float4 a = s[0], b = s[1];
    bf16x8 o;
    o[0] = f2bf(a.x); o[1] = f2bf(a.y); o[2] = f2bf(a.z); o[3] = f2bf(a.w);
    o[4] = f2bf(b.x); o[5] = f2bf(b.y); o[6] = f2bf(b.z); o[7] = f2bf(b.w);
    reinterpret_cast<bf16x8*>(dst)[i] = o;
}

__global__ __launch_bounds__(256) void cast_w_kernel(
    const float* __restrict__ Wq, const float* __restrict__ Wk,
    const float* __restrict__ Wv, short* __restrict__ dst)
{
    const int z = blockIdx.y;
    const float* src = (z == 0) ? Wq : ((z == 1) ? Wk : Wv);
    const size_t i = (size_t)blockIdx.x * 256 + threadIdx.x;
    const float4* s = reinterpret_cast<const float4*>(src) + i * 2;
    const float4 a = s[0], b = s[1];
    bf16x8 o;
    o[0] = f2bf(a.x); o[1] = f2bf(a.y); o[2] = f2bf(a.z); o[3] = f2bf(a.w);
    o[4] = f2bf(b.x); o[5] = f2bf(b.y); o[6] = f2bf(b.z); o[7] = f2bf(b.w);
    reinterpret_cast<bf16x8*>(dst + (size_t)z * HID * HID)[i] = o;
}

// ---------------------------------------------------------------------------
// QKV projection, LDS-staged. Tile 128x128, BK=64, dbuf 64KB.
// Q output pre-scaled by 0.125*log2e (folds the softmax scale).
// ---------------------------------------------------------------------------
__global__ __launch_bounds__(256) void qkv_proj_kernel(
    const short* __restrict__ hsb, const short* __restrict__ Wb,
    const float* __restrict__ bq, const float* __restrict__ bk,
    const float* __restrict__ bv,
    short* __restrict__ Qb, short* __restrict__ Kb, short* __restrict__ Vt)
{
    __shared__ __align__(16) char lds[65536];
    const int z = blockIdx.z;
    const float* bias = (z == 0) ? bq : ((z == 1) ? bk : bv);

    const int lane = threadIdx.x & 63;
    const int w    = threadIdx.x >> 6;
    const int lr = lane & 15, hi = lane >> 4;
    const int wi = w >> 1, wj = w & 1;

    const short* Ag; const short* Bg; int ar0, br0;
    if (z < 2) { Ag = Wb + (size_t)z * HID * HID; ar0 = blockIdx.x * 128;
                 Bg = hsb;                        br0 = blockIdx.y * 128; }
    else       { Ag = hsb;                        ar0 = blockIdx.y * 128;
                 Bg = Wb + (size_t)2 * HID * HID; br0 = blockIdx.x * 128; }

    const int rsub = lane >> 3;
    const int c16  = (lane & 7) ^ rsub;

    auto stage = [&](int t, int buf) {
        const int k0 = t * PBK;
#pragma unroll
        for (int c = 0; c < 4; ++c) {
            const int ch = w * 4 + c;
            const int row = ch * 8 + rsub;
            glds16(Ag + (size_t)(ar0 + row) * HID + k0 + c16 * 8,
                   lds + buf * 16384 + ch * 1024);
            glds16(Bg + (size_t)(br0 + row) * HID + k0 + c16 * 8,
                   lds + 32768 + buf * 16384 + ch * 1024);
        }
    };

    stage(0, 0);
    f32x4 acc[4][4] = {};

    for (int t = 0; t < PNT; ++t) {
        asm volatile("s_waitcnt vmcnt(0)" ::: "memory");
        __builtin_amdgcn_s_barrier();
        __builtin_amdgcn_sched_barrier(0);
        if (t + 1 < PNT) stage(t + 1, (t + 1) & 1);
        const char* LA = lds + (t & 1) * 16384;
        const char* LB = lds + 32768 + (t & 1) * 16384;
#pragma unroll
        for (int ks = 0; ks < 2; ++ks) {
            bf16x8 af[4], bf_[4];
#pragma unroll
            for (int i = 0; i < 4; ++i) {
                const int rowA = wi * 64 + i * 16 + lr;
                af[i] = *reinterpret_cast<const bf16x8*>(
                    LA + rowA * 128 + (((ks * 4 + hi) ^ (rowA & 7)) << 4));
                const int rowB = wj * 64 + i * 16 + lr;
                bf_[i] = *reinterpret_cast<const bf16x8*>(
                    LB + rowB * 128 + (((ks * 4 + hi) ^ (rowB & 7)) << 4));
            }
            __builtin_amdgcn_s_setprio(1);
#pragma unroll
            for (int ia = 0; ia < 4; ++ia)
#pragma unroll
                for (int ib = 0; ib < 4; ++ib)
                    acc[ia][ib] = __builtin_amdgcn_mfma_f32_16x16x32_bf16(
                        af[ia], bf_[ib], acc[ia][ib], 0, 0, 0);
            __builtin_amdgcn_s_setprio(0);
        }
    }

    const float SCQ = 0.125f * 1.44269504088896340736f;
    if (z < 2) {
        short* outp = (z == 0) ? Qb : Kb;
        const float sc = (z == 0) ? SCQ : 1.0f;
#pragma unroll
        for (int ia = 0; ia < 4; ++ia) {
            const int nb = ar0 + wi * 64 + ia * 16 + hi * 4;
            const float4 b4 = *reinterpret_cast<const float4*>(bias + nb);
#pragma unroll
            for (int ib = 0; ib < 4; ++ib) {
                const int m = br0 + wj * 64 + ib * 16 + lr;
                s16x4 v;
                v[0] = f2bf((acc[ia][ib][0] + b4.x) * sc);
                v[1] = f2bf((acc[ia][ib][1] + b4.y) * sc);
                v[2] = f2bf((acc[ia][ib][2] + b4.z) * sc);
                v[3] = f2bf((acc[ia][ib][3] + b4.w) * sc);
                *reinterpret_cast<s16x4*>(outp + (size_t)m * HID + nb) = v;
            }
        }
    } else {
#pragma unroll
        for (int ib = 0; ib < 4; ++ib) {
            const int n = br0 + wj * 64 + ib * 16 + lr;
            const float bb = bias[n];
#pragma unroll
            for (int ia = 0; ia < 4; ++ia) {
                const int mb = ar0 + wi * 64 + ia * 16 + hi * 4;
                s16x4 v;
                v[0] = f2bf(acc[ia][ib][0] + bb);
                v[1] = f2bf(acc[ia][ib][1] + bb);
                v[2] = f2bf(acc[ia][ib][2] + bb);
                v[3] = f2bf(acc[ia][ib][3] + bb);
                *reinterpret_cast<s16x4*>(Vt + (size_t)n * SEQ + mb) = v;
            }
        }
    }
}

// ---------------------------------------------------------------------------
// Flash attention: 32-q blocks, grid (SEQ/32, NHEAD) = 1536 = 6.0/CU.
// 4 waves = (qh 2) x (kh 2); each wave 16q x 32k per tile. LDS 40KB ->
// 4 blocks/CU resident; independent blocks at different loop phases hide
// each other's barrier/latency stalls.
// Per-lane deferred-max softmax (zero cross-lane in common path), zero-
// shuffle P via key-permuted QK^T, mask bf16 in LDS expanded to C-init.
// LDS: K dbuf 2x8KB @0, V dbuf 2x8KB @16384, mask bf16 8KB @32768. 40KB.
// ---------------------------------------------------------------------------
__global__ __launch_bounds__(256, 4) void attn_kernel(
    const short* __restrict__ Qb, const short* __restrict__ Kb,
    const short* __restrict__ Vt, const float* __restrict__ maskp,
    float* __restrict__ out)
{
    __shared__ __align__(16) char lds[40960];
    const int tid  = threadIdx.x;
    const int lane = tid & 63;
    const int w    = tid >> 6;
    const int lr = lane & 15, hi = lane >> 4;
    const int qh = w >> 1, kh = w & 1;       // wave = (q-group, key-half)
    const int h  = blockIdx.y;
    const int q0 = blockIdx.x * 32 + qh * 16;
    const float ML = 1.44269504088896340736f;

    const int srow = lane >> 3;
    auto stage = [&](int t, int buf) {
        const int kt = t * KVB;
#pragma unroll
        for (int j = 0; j < 2; ++j) {
            const int ch  = w * 2 + j;
            const int row = ch * 8 + srow;
            const int c16 = (lane & 7) ^ srow ^ ((ch & 1) << 2);
            glds16(Kb + (size_t)(kt + row) * HID + h * HDIM + c16 * 8,
                   lds + buf * 8192 + ch * 1024);
            glds16(Vt + (size_t)(h * HDIM + row) * SEQ + kt + c16 * 8,
                   lds + 16384 + buf * 8192 + ch * 1024);
        }
    };

    stage(0, 0);   // in flight across mask/Q staging

    // stage mask*log2e as bf16 (once): 4096 values, 16 per thread
    {
        short* mb = (short*)(lds + 32768);
        const int base = tid * 16;
        float4 m4[4];
#pragma unroll
        for (int i = 0; i < 4; ++i)
            m4[i] = *reinterpret_cast<const float4*>(maskp + base + i * 4);
        union { unsigned u[8]; } pk;
#pragma unroll
        for (int i = 0; i < 4; ++i) {
            pk.u[i * 2]     = cvtpk(m4[i].x * ML, m4[i].y * ML);
            pk.u[i * 2 + 1] = cvtpk(m4[i].z * ML, m4[i].w * ML);
        }
        *reinterpret_cast<uint4*>(mb + base)     = *reinterpret_cast<uint4*>(&pk.u[0]);
        *reinterpret_cast<uint4*>(mb + base + 8) = *reinterpret_cast<uint4*>(&pk.u[4]);
    }

    // Q fragments [ks]: Q[q0+lr][ks*32 + hi*8 ..+7] (pre-scaled)
    const short* qp = Qb + (size_t)(q0 + lr) * HID + h * HDIM + hi * 8;
    const bf16x8 qf0 = *reinterpret_cast<const bf16x8*>(qp);
    const bf16x8 qf1 = *reinterpret_cast<const bf16x8*>(qp + 32);

    __syncthreads();   // mask visible to all waves

    f32x4 acc[4] = {};                        // [dg]
    float m_r = -INFINITY, ls = 0.f;
    const int kbase = ((lr >> 2) * 8) + (lr & 3) + kh * 32;  // key-permutation
    const int fv    = (lr & 7) ^ (((lr >> 3) & 1) << 2);     // V-row swizzle
    const int vslot = ((kh * 4 + hi) ^ fv) << 4;
    const short* mlds = (const short*)(lds + 32768);

    for (int t = 0; t < NT; ++t) {
        asm volatile("s_waitcnt vmcnt(0)" ::: "memory");  // own stage(t) landed
        __builtin_amdgcn_s_barrier();                     // all waves' stage(t) landed
        __builtin_amdgcn_sched_barrier(0);
        if (t + 1 < NT) stage(t + 1, (t + 1) & 1);

        // ---- mask C-init: keys kh*32 + hi*8 + (0..7), bf16 -> f32
        const bf16x8 mv = *reinterpret_cast<const bf16x8*>(
            mlds + t * KVB + kh * 32 + hi * 8);
        f32x4 ci0, ci1;
#pragma unroll
        for (int r = 0; r < 4; ++r) {
            ci0[r] = bf2f((unsigned short)mv[r]);
            ci1[r] = bf2f((unsigned short)mv[4 + r]);
        }

        // ---- QK^T, key-permuted: MFMA kg -> keys kh*32 + hi*8 + kg*4 + r,
        //      q = lr. C-init = mask*log2e.
        const char* KT = lds + (t & 1) * 8192;
        float s2[2][4];
#pragma unroll
        for (int kg = 0; kg < 2; ++kg) {
            const int row = kbase + kg * 4;
            const int fr  = (row & 7) ^ ((row >> 1) & 4);
            const bf16x8 kf0 = *reinterpret_cast<const bf16x8*>(
                KT + row * 128 + ((hi ^ fr) << 4));
            const bf16x8 kf1 = *reinterpret_cast<const bf16x8*>(
                KT + row * 128 + (((4 + hi) ^ fr) << 4));
            f32x4 zz = (kg == 0) ? ci0 : ci1;
            __builtin_amdgcn_s_setprio(1);
            zz = __builtin_amdgcn_mfma_f32_16x16x32_bf16(kf0, qf0, zz, 0, 0, 0);
            zz = __builtin_amdgcn_mfma_f32_16x16x32_bf16(kf1, qf1, zz, 0, 0, 0);
            __builtin_amdgcn_s_setprio(0);
            s2[kg][0] = zz[0]; s2[kg][1] = zz[1];
            s2[kg][2] = zz[2]; s2[kg][3] = zz[3];
        }

        // ---- e = exp2(s2 - m), per-lane (NO cross-lane ops in common path)
        float e_[2][4];
#pragma unroll
        for (int kg = 0; kg < 2; ++kg)
#pragma unroll
            for (int r = 0; r < 4; ++r)
                e_[kg][r] = exp2f(s2[kg][r] - m_r);

        // ---- per-lane violation check: any e > 2^8 (<=> s - m > 8)?
        const float pa = max3f(e_[0][0], e_[0][1], e_[0][2]);
        const float pb = max3f(e_[0][3], e_[1][0], e_[1][1]);
        const float pc = max3f(e_[1][2], e_[1][3], pa);
        const float pmax = fmaxf(pb, pc);
        if (__ballot(pmax > 256.f)) {
            // rare recovery: full cross-lane max, rescale, recompute e
            float t_ = fmaxf(
                max3f(s2[0][0], s2[0][1], s2[0][2]),
                max3f(fmaxf(s2[0][3], s2[1][0]),
                      fmaxf(s2[1][1], s2[1][2]), s2[1][3]));
            t_ = fmaxf(t_, __shfl_xor(t_, 16));
            t_ = fmaxf(t_, __shfl_xor(t_, 32));
            const float newm = fmaxf(m_r, t_);
            const float sc = exp2f(fmaxf(m_r - newm, -128.f));
            ls *= sc;
#pragma unroll
            for (int dg = 0; dg < 4; ++dg) acc[dg] *= sc;
            m_r = newm;
#pragma unroll
            for (int kg = 0; kg < 2; ++kg)
#pragma unroll
                for (int r = 0; r < 4; ++r)
                    e_[kg][r] = exp2f(s2[kg][r] - newm);
        }

        // ---- accumulate l, pack P (zero-shuffle: e's ARE the PV B-frag)
        ls += ((e_[0][0] + e_[0][1]) + (e_[0][2] + e_[0][3]))
            + ((e_[1][0] + e_[1][1]) + (e_[1][2] + e_[1][3]));
        union { unsigned u[4]; bf16x8 v; } P;
        P.u[0] = cvtpk(e_[0][0], e_[0][1]);
        P.u[1] = cvtpk(e_[0][2], e_[0][3]);
        P.u[2] = cvtpk(e_[1][0], e_[1][1]);
        P.u[3] = cvtpk(e_[1][2], e_[1][3]);

        // ---- PV: O[d][q] += V[d][k]·P[k][q] over this wave's 32 keys
        const char* VT = lds + 16384 + (t & 1) * 8192;
#pragma unroll
        for (int dg = 0; dg < 4; ++dg) {
            const bf16x8 vf = *reinterpret_cast<const bf16x8*>(
                VT + (dg * 16 + lr) * 128 + vslot);
            __builtin_amdgcn_s_setprio(1);
            acc[dg] = __builtin_amdgcn_mfma_f32_16x16x32_bf16(vf, P.v, acc[dg], 0, 0, 0);
            __builtin_amdgcn_s_setprio(0);
        }
    }

    // ---- reduce l across hi-groups
    {
        float t_ = ls;
        t_ += __shfl_xor(t_, 16);
        t_ += __shfl_xor(t_, 32);
        ls = t_;
    }

    // ---- flash-merge the two key-halves through LDS (reuse K/V buffers)
    __syncthreads();
    float* mg  = (float*)lds;                 // [qh][dg][lane] f32x4 = 8KB
    float* mlb = (float*)(lds + 8192);        // [qh][lane][2]  = 1KB
    if (kh == 1) {
        float2 v0; v0.x = m_r; v0.y = ls;
        *reinterpret_cast<float2*>(mlb + (qh * 64 + lane) * 2) = v0;
#pragma unroll
        for (int dg = 0; dg < 4; ++dg)
            *reinterpret_cast<f32x4*>(
                mg + ((qh * 4 + dg) * 64 + lane) * 4) = acc[dg];
    }
    __syncthreads();
    if (kh == 0) {
        const float2 v = *reinterpret_cast<const float2*>(
            mlb + (qh * 64 + lane) * 2);
        const float mm = fmaxf(m_r, v.x);
        const float sc0 = exp2f(fmaxf(m_r - mm, -128.f));
        const float sc1 = exp2f(fmaxf(v.x - mm, -128.f));
        const float rl = 1.0f / (ls * sc0 + v.y * sc1);
#pragma unroll
        for (int dg = 0; dg < 4; ++dg) {
            const f32x4 o1 = *reinterpret_cast<const f32x4*>(
                mg + ((qh * 4 + dg) * 64 + lane) * 4);
            const f32x4 of = (acc[dg] * sc0 + o1 * sc1) * rl;
            float* op = out + (size_t)(q0 + lr) * HID + h * HDIM + dg * 16 + hi * 4;
            *reinterpret_cast<f32x4*>(op) = of;
        }
    }
}

// ---------------------------------------------------------------------------
extern "C" void kernel_launch(void* const* d_in, const int* in_sizes, int n_in,
                              void* d_out, int out_size, void* d_ws, size_t ws_size,
                              hipStream_t stream) {
    const float* hs   = (const float*)d_in[0];
    const float* mask = (const float*)d_in[1];
    const float* Wq   = (const float*)d_in[2];
    const float* bq   = (const float*)d_in[3];
    const float* Wk   = (const float*)d_in[4];
    const float* bk   = (const float*)d_in[5];
    const float* Wv   = (const float*)d_in[6];
    const float* bv   = (const float*)d_in[7];

    short* Qb = (short*)d_ws;                       // bf16 [SEQ][HID], pre-scaled
    short* Kb = Qb + (size_t)SEQ * HID;             // bf16 [SEQ][HID]
    short* Vt = Kb + (size_t)SEQ * HID;             // bf16 [HID][SEQ]
    float* out = (float*)d_out;

    // bf16 scratch carved from d_out (attn overwrites it at the very end)
    short* hsb = (short*)d_out;
    short* Wb  = hsb + (size_t)SEQ * HID;

    cast_bf16_kernel<<<dim3(SEQ * HID / 2048), 256, 0, stream>>>(hs, hsb);
    cast_w_kernel<<<dim3(HID * HID / 2048, 3), 256, 0, stream>>>(Wq, Wk, Wv, Wb);

    qkv_proj_kernel<<<dim3(HID / 128, SEQ / 128, 3), 256, 0, stream>>>(
        hsb, Wb, bq, bk, bv, Qb, Kb, Vt);

    attn_kernel<<<dim3(SEQ / 32, NHEAD), 256, 0, stream>>>(Qb, Kb, Vt, mask, out);
}

// Round 8
// 130.564 us; speedup vs baseline: 1.1634x; 1.1634x over previous
//
#include <hip/hip_runtime.h>
#include <hip/hip_bf16.h>

#define SEQ 4096
#define HID 768
#define NHEAD 12
#define HDIM 64
#define KVB 64
#define NT (SEQ / KVB)   // 64
#define PBK 64
#define PNT (HID / PBK)  // 12

typedef __attribute__((ext_vector_type(8))) short bf16x8;
typedef __attribute__((ext_vector_type(4))) float f32x4;
typedef __attribute__((ext_vector_type(4))) short s16x4;

static __device__ __forceinline__ short f2bf(float f) {
    unsigned u = __builtin_bit_cast(unsigned, f);
    unsigned r = (u + 0x7fffu + ((u >> 16) & 1u)) >> 16;
    return (short)r;
}
static __device__ __forceinline__ unsigned cvtpk(float lo, float hi) {
    unsigned r;
    asm("v_cvt_pk_bf16_f32 %0, %1, %2" : "=v"(r) : "v"(lo), "v"(hi));
    return r;
}
static __device__ __forceinline__ float max3f(float a, float b, float c) {
    float r;
    asm("v_max3_f32 %0, %1, %2, %3" : "=v"(r) : "v"(a), "v"(b), "v"(c));
    return r;
}
static __device__ __forceinline__ void glds16(const void* g, void* l) {
    __builtin_amdgcn_global_load_lds(
        (const __attribute__((address_space(1))) unsigned*)g,
        (__attribute__((address_space(3))) unsigned*)l, 16, 0, 0);
}

// ---------------------------------------------------------------------------
// fp32 -> bf16 casts
// ---------------------------------------------------------------------------
__global__ __launch_bounds__(256) void cast_bf16_kernel(
    const float* __restrict__ src, short* __restrict__ dst)
{
    const size_t i = (size_t)blockIdx.x * 256 + threadIdx.x;
    const float4* s = reinterpret_cast<const float4*>(src) + i * 2;
    const float4 a = s[0], b = s[1];
    bf16x8 o;
    o[0] = f2bf(a.x); o[1] = f2bf(a.y); o[2] = f2bf(a.z); o[3] = f2bf(a.w);
    o[4] = f2bf(b.x); o[5] = f2bf(b.y); o[6] = f2bf(b.z); o[7] = f2bf(b.w);
    reinterpret_cast<bf16x8*>(dst)[i] = o;
}

__global__ __launch_bounds__(256) void cast_w_kernel(
    const float* __restrict__ Wq, const float* __restrict__ Wk,
    const float* __restrict__ Wv, short* __restrict__ dst)
{
    const int z = blockIdx.y;
    const float* src = (z == 0) ? Wq : ((z == 1) ? Wk : Wv);
    const size_t i = (size_t)blockIdx.x * 256 + threadIdx.x;
    const float4* s = reinterpret_cast<const float4*>(src) + i * 2;
    const float4 a = s[0], b = s[1];
    bf16x8 o;
    o[0] = f2bf(a.x); o[1] = f2bf(a.y); o[2] = f2bf(a.z); o[3] = f2bf(a.w);
    o[4] = f2bf(b.x); o[5] = f2bf(b.y); o[6] = f2bf(b.z); o[7] = f2bf(b.w);
    reinterpret_cast<bf16x8*>(dst + (size_t)z * HID * HID)[i] = o;
}

// ---------------------------------------------------------------------------
// QKV projection, LDS-staged. Tile 128x128, BK=64, dbuf 64KB.
// Q output pre-scaled by 0.125*log2e (folds the softmax scale).
// ---------------------------------------------------------------------------
__global__ __launch_bounds__(256) void qkv_proj_kernel(
    const short* __restrict__ hsb, const short* __restrict__ Wb,
    const float* __restrict__ bq, const float* __restrict__ bk,
    const float* __restrict__ bv,
    short* __restrict__ Qb, short* __restrict__ Kb, short* __restrict__ Vt)
{
    __shared__ __align__(16) char lds[65536];
    const int z = blockIdx.z;
    const float* bias = (z == 0) ? bq : ((z == 1) ? bk : bv);

    const int lane = threadIdx.x & 63;
    const int w    = threadIdx.x >> 6;
    const int lr = lane & 15, hi = lane >> 4;
    const int wi = w >> 1, wj = w & 1;

    const short* Ag; const short* Bg; int ar0, br0;
    if (z < 2) { Ag = Wb + (size_t)z * HID * HID; ar0 = blockIdx.x * 128;
                 Bg = hsb;                        br0 = blockIdx.y * 128; }
    else       { Ag = hsb;                        ar0 = blockIdx.y * 128;
                 Bg = Wb + (size_t)2 * HID * HID; br0 = blockIdx.x * 128; }

    const int rsub = lane >> 3;
    const int c16  = (lane & 7) ^ rsub;

    auto stage = [&](int t, int buf) {
        const int k0 = t * PBK;
#pragma unroll
        for (int c = 0; c < 4; ++c) {
            const int ch = w * 4 + c;
            const int row = ch * 8 + rsub;
            glds16(Ag + (size_t)(ar0 + row) * HID + k0 + c16 * 8,
                   lds + buf * 16384 + ch * 1024);
            glds16(Bg + (size_t)(br0 + row) * HID + k0 + c16 * 8,
                   lds + 32768 + buf * 16384 + ch * 1024);
        }
    };

    stage(0, 0);
    f32x4 acc[4][4] = {};

    for (int t = 0; t < PNT; ++t) {
        asm volatile("s_waitcnt vmcnt(0)" ::: "memory");
        __builtin_amdgcn_s_barrier();
        __builtin_amdgcn_sched_barrier(0);
        if (t + 1 < PNT) stage(t + 1, (t + 1) & 1);
        const char* LA = lds + (t & 1) * 16384;
        const char* LB = lds + 32768 + (t & 1) * 16384;
#pragma unroll
        for (int ks = 0; ks < 2; ++ks) {
            bf16x8 af[4], bf_[4];
#pragma unroll
            for (int i = 0; i < 4; ++i) {
                const int rowA = wi * 64 + i * 16 + lr;
                af[i] = *reinterpret_cast<const bf16x8*>(
                    LA + rowA * 128 + (((ks * 4 + hi) ^ (rowA & 7)) << 4));
                const int rowB = wj * 64 + i * 16 + lr;
                bf_[i] = *reinterpret_cast<const bf16x8*>(
                    LB + rowB * 128 + (((ks * 4 + hi) ^ (rowB & 7)) << 4));
            }
            __builtin_amdgcn_s_setprio(1);
#pragma unroll
            for (int ia = 0; ia < 4; ++ia)
#pragma unroll
                for (int ib = 0; ib < 4; ++ib)
                    acc[ia][ib] = __builtin_amdgcn_mfma_f32_16x16x32_bf16(
                        af[ia], bf_[ib], acc[ia][ib], 0, 0, 0);
            __builtin_amdgcn_s_setprio(0);
        }
    }

    const float SCQ = 0.125f * 1.44269504088896340736f;
    if (z < 2) {
        short* outp = (z == 0) ? Qb : Kb;
        const float sc = (z == 0) ? SCQ : 1.0f;
#pragma unroll
        for (int ia = 0; ia < 4; ++ia) {
            const int nb = ar0 + wi * 64 + ia * 16 + hi * 4;
            const float4 b4 = *reinterpret_cast<const float4*>(bias + nb);
#pragma unroll
            for (int ib = 0; ib < 4; ++ib) {
                const int m = br0 + wj * 64 + ib * 16 + lr;
                s16x4 v;
                v[0] = f2bf((acc[ia][ib][0] + b4.x) * sc);
                v[1] = f2bf((acc[ia][ib][1] + b4.y) * sc);
                v[2] = f2bf((acc[ia][ib][2] + b4.z) * sc);
                v[3] = f2bf((acc[ia][ib][3] + b4.w) * sc);
                *reinterpret_cast<s16x4*>(outp + (size_t)m * HID + nb) = v;
            }
        }
    } else {
#pragma unroll
        for (int ib = 0; ib < 4; ++ib) {
            const int n = br0 + wj * 64 + ib * 16 + lr;
            const float bb = bias[n];
#pragma unroll
            for (int ia = 0; ia < 4; ++ia) {
                const int mb = ar0 + wi * 64 + ia * 16 + hi * 4;
                s16x4 v;
                v[0] = f2bf(acc[ia][ib][0] + bb);
                v[1] = f2bf(acc[ia][ib][1] + bb);
                v[2] = f2bf(acc[ia][ib][2] + bb);
                v[3] = f2bf(acc[ia][ib][3] + bb);
                *reinterpret_cast<s16x4*>(Vt + (size_t)n * SEQ + mb) = v;
            }
        }
    }
}

// ---------------------------------------------------------------------------
// Flash attention (r6 geometry + VALU diet): 64q blocks, 4 waves =
// (qh 2) x (kh 2), each wave 32q x 32k. Tile loop unrolled x2 so buffer
// indices are compile-time; ALL LDS read pointers precomputed; staging uses
// incrementing global pointers + precomputed lane offsets; mask staged f32.
// Per-lane deferred-max softmax; zero-shuffle P via key-permuted QK^T.
// LDS: K dbuf 2x8KB @0, V dbuf 2x8KB @16384, mask f32 16KB @32768. 48KB.
// ---------------------------------------------------------------------------
__global__ __launch_bounds__(256, 3) void attn_kernel(
    const short* __restrict__ Qb, const short* __restrict__ Kb,
    const short* __restrict__ Vt, const float* __restrict__ maskp,
    float* __restrict__ out)
{
    __shared__ __align__(16) char lds[49152];
    const int tid  = threadIdx.x;
    const int lane = tid & 63;
    const int w    = tid >> 6;
    const int lr = lane & 15, hi = lane >> 4;
    const int qh = w >> 1, kh = w & 1;       // wave = (q-half, key-half)
    const int h  = blockIdx.y;
    const int q0 = blockIdx.x * 64 + qh * 32;
    const float ML = 1.44269504088896340736f;

    // ---- staging: per-lane source offsets (elements) + LDS dests
    const int srow = lane >> 3;
    int sofK[2], sofV[2];
    char* sdK[2][2]; char* sdV[2][2];
#pragma unroll
    for (int j = 0; j < 2; ++j) {
        const int ch  = w * 2 + j;
        const int row = ch * 8 + srow;
        const int c16 = (lane & 7) ^ srow ^ ((ch & 1) << 2);
        sofK[j] = row * HID + c16 * 8;
        sofV[j] = row * SEQ + c16 * 8;
#pragma unroll
        for (int b = 0; b < 2; ++b) {
            sdK[b][j] = lds + b * 8192 + ch * 1024;
            sdV[b][j] = lds + 16384 + b * 8192 + ch * 1024;
        }
    }
    const short* gK = Kb + h * HDIM;                    // advances by KVB*HID
    const short* gV = Vt + (size_t)h * HDIM * SEQ;      // advances by KVB

    auto stagep = [&](int buf) {
        glds16(gK + sofK[0], sdK[buf][0]);
        glds16(gK + sofK[1], sdK[buf][1]);
        glds16(gV + sofV[0], sdV[buf][0]);
        glds16(gV + sofV[1], sdV[buf][1]);
        gK += KVB * HID; gV += KVB;
    };

    stagep(0);   // tile 0 in flight across mask/Q staging

    // ---- stage mask*log2e as f32 (once): 4096 floats, 16 per thread
    {
        float* mb = (float*)(lds + 32768);
        const int base = tid * 16;
#pragma unroll
        for (int i = 0; i < 4; ++i) {
            float4 m4 = *reinterpret_cast<const float4*>(maskp + base + i * 4);
            m4.x *= ML; m4.y *= ML; m4.z *= ML; m4.w *= ML;
            *reinterpret_cast<float4*>(mb + base + i * 4) = m4;
        }
    }

    // ---- Q fragments (pre-scaled by 0.125*log2e at projection)
    const short* qp = Qb + (size_t)(q0 + lr) * HID + h * HDIM + hi * 8;
    const bf16x8 qf0 = *reinterpret_cast<const bf16x8*>(qp);
    const bf16x8 qf1 = *reinterpret_cast<const bf16x8*>(qp + 32);
    bf16x8 qg0, qg1;   // second q-group (rows +16)
    {
        const short* qp2 = qp + 16 * HID;
        qg0 = *reinterpret_cast<const bf16x8*>(qp2);
        qg1 = *reinterpret_cast<const bf16x8*>(qp2 + 32);
    }

    // ---- precomputed LDS read pointers (both buffers, all fragments)
    const int kbase = ((lr >> 2) * 8) + (lr & 3) + kh * 32;  // key-permutation
    const int fv    = (lr & 7) ^ (((lr >> 3) & 1) << 2);     // V-row swizzle
    const int vslot = ((kh * 4 + hi) ^ fv) << 4;
    const char* kp[2][2][2];
    const char* vp[2][4];
#pragma unroll
    for (int b = 0; b < 2; ++b) {
#pragma unroll
        for (int kg = 0; kg < 2; ++kg) {
            const int row = kbase + kg * 4;
            const int fr  = (row & 7) ^ ((row >> 1) & 4);
            kp[b][kg][0] = lds + b * 8192 + row * 128 + ((hi ^ fr) << 4);
            kp[b][kg][1] = lds + b * 8192 + row * 128 + (((4 + hi) ^ fr) << 4);
        }
#pragma unroll
        for (int dg = 0; dg < 4; ++dg)
            vp[b][dg] = lds + 16384 + b * 8192 + (dg * 16 + lr) * 128 + vslot;
    }
    const float* mptr = (const float*)(lds + 32768) + kh * 32 + hi * 8;

    __syncthreads();   // mask visible to all waves

    f32x4 acc[4][2] = {};                     // [dg][qg]
    float m_r[2] = {-INFINITY, -INFINITY};
    float ls[2]  = {0.f, 0.f};

    auto tile = [&](int tt, int buf) {
        asm volatile("s_waitcnt vmcnt(0)" ::: "memory");  // stage(tt) landed
        __builtin_amdgcn_s_barrier();
        __builtin_amdgcn_sched_barrier(0);
        if (tt + 1 < NT) stagep(buf ^ 1);

        // ---- QK^T (key-permuted), C-init = mask*log2e
        const f32x4 ci0 = *reinterpret_cast<const f32x4*>(mptr);
        const f32x4 ci1 = *reinterpret_cast<const f32x4*>(mptr + 4);
        mptr += KVB;
        const bf16x8 kf00 = *reinterpret_cast<const bf16x8*>(kp[buf][0][0]);
        const bf16x8 kf01 = *reinterpret_cast<const bf16x8*>(kp[buf][0][1]);
        const bf16x8 kf10 = *reinterpret_cast<const bf16x8*>(kp[buf][1][0]);
        const bf16x8 kf11 = *reinterpret_cast<const bf16x8*>(kp[buf][1][1]);
        f32x4 z[2][2];   // [kg][qg]
        z[0][0] = ci0; z[0][1] = ci0; z[1][0] = ci1; z[1][1] = ci1;
        __builtin_amdgcn_s_setprio(1);
        z[0][0] = __builtin_amdgcn_mfma_f32_16x16x32_bf16(kf00, qf0, z[0][0], 0, 0, 0);
        z[0][0] = __builtin_amdgcn_mfma_f32_16x16x32_bf16(kf01, qf1, z[0][0], 0, 0, 0);
        z[0][1] = __builtin_amdgcn_mfma_f32_16x16x32_bf16(kf00, qg0, z[0][1], 0, 0, 0);
        z[0][1] = __builtin_amdgcn_mfma_f32_16x16x32_bf16(kf01, qg1, z[0][1], 0, 0, 0);
        z[1][0] = __builtin_amdgcn_mfma_f32_16x16x32_bf16(kf10, qf0, z[1][0], 0, 0, 0);
        z[1][0] = __builtin_amdgcn_mfma_f32_16x16x32_bf16(kf11, qf1, z[1][0], 0, 0, 0);
        z[1][1] = __builtin_amdgcn_mfma_f32_16x16x32_bf16(kf10, qg0, z[1][1], 0, 0, 0);
        z[1][1] = __builtin_amdgcn_mfma_f32_16x16x32_bf16(kf11, qg1, z[1][1], 0, 0, 0);
        __builtin_amdgcn_s_setprio(0);

        // ---- e = exp2(z - m), per-lane (no cross-lane ops in common path)
        float e_[2][2][4];
#pragma unroll
        for (int kg = 0; kg < 2; ++kg)
#pragma unroll
            for (int qg = 0; qg < 2; ++qg)
#pragma unroll
                for (int r = 0; r < 4; ++r)
                    e_[kg][qg][r] = exp2f(z[kg][qg][r] - m_r[qg]);

        // ---- per-lane violation check: any e > 2^8?
        const float pa = max3f(e_[0][0][0], e_[0][0][1], e_[0][0][2]);
        const float pb = max3f(e_[0][0][3], e_[0][1][0], e_[0][1][1]);
        const float pc = max3f(e_[0][1][2], e_[0][1][3], e_[1][0][0]);
        const float pd = max3f(e_[1][0][1], e_[1][0][2], e_[1][0][3]);
        const float pe = max3f(e_[1][1][0], e_[1][1][1], e_[1][1][2]);
        const float pmax = max3f(fmaxf(pa, pb), fmaxf(pc, pd),
                                 fmaxf(pe, e_[1][1][3]));
        if (__ballot(pmax > 256.f)) {
            // rare recovery: full cross-lane max, rescale, recompute e
#pragma unroll
            for (int qg = 0; qg < 2; ++qg) {
                float t_ = fmaxf(
                    max3f(z[0][qg][0], z[0][qg][1], z[0][qg][2]),
                    max3f(fmaxf(z[0][qg][3], z[1][qg][0]),
                          fmaxf(z[1][qg][1], z[1][qg][2]), z[1][qg][3]));
                t_ = fmaxf(t_, __shfl_xor(t_, 16));
                t_ = fmaxf(t_, __shfl_xor(t_, 32));
                const float newm = fmaxf(m_r[qg], t_);
                const float sc = exp2f(fmaxf(m_r[qg] - newm, -128.f));
                ls[qg] *= sc;
#pragma unroll
                for (int dg = 0; dg < 4; ++dg) acc[dg][qg] *= sc;
                m_r[qg] = newm;
#pragma unroll
                for (int kg = 0; kg < 2; ++kg)
#pragma unroll
                    for (int r = 0; r < 4; ++r)
                        e_[kg][qg][r] = exp2f(z[kg][qg][r] - newm);
            }
        }

        // ---- accumulate l, pack P (zero-shuffle)
        union { unsigned u[4]; bf16x8 v; } P[2];
#pragma unroll
        for (int qg = 0; qg < 2; ++qg) {
            ls[qg] += ((e_[0][qg][0] + e_[0][qg][1]) + (e_[0][qg][2] + e_[0][qg][3]))
                    + ((e_[1][qg][0] + e_[1][qg][1]) + (e_[1][qg][2] + e_[1][qg][3]));
            P[qg].u[0] = cvtpk(e_[0][qg][0], e_[0][qg][1]);
            P[qg].u[1] = cvtpk(e_[0][qg][2], e_[0][qg][3]);
            P[qg].u[2] = cvtpk(e_[1][qg][0], e_[1][qg][1]);
            P[qg].u[3] = cvtpk(e_[1][qg][2], e_[1][qg][3]);
        }

        // ---- PV: O[d][q] += V[d][k]·P[k][q] over this wave's 32 keys
#pragma unroll
        for (int dg = 0; dg < 4; ++dg) {
            const bf16x8 vf = *reinterpret_cast<const bf16x8*>(vp[buf][dg]);
            __builtin_amdgcn_s_setprio(1);
            acc[dg][0] = __builtin_amdgcn_mfma_f32_16x16x32_bf16(vf, P[0].v, acc[dg][0], 0, 0, 0);
            acc[dg][1] = __builtin_amdgcn_mfma_f32_16x16x32_bf16(vf, P[1].v, acc[dg][1], 0, 0, 0);
            __builtin_amdgcn_s_setprio(0);
        }
    };

    for (int t = 0; t < NT; t += 2) {
        tile(t, 0);
        tile(t + 1, 1);
    }

    // ---- reduce l across hi-groups (per qg)
#pragma unroll
    for (int qg = 0; qg < 2; ++qg) {
        float t_ = ls[qg];
        t_ += __shfl_xor(t_, 16);
        t_ += __shfl_xor(t_, 32);
        ls[qg] = t_;
    }

    // ---- flash-merge the two key-halves through LDS (reuse K/V buffers)
    __syncthreads();
    float* mg  = (float*)lds;                 // [qh][dg*2+qg][lane] f32x4 = 16KB
    float* mlb = (float*)(lds + 16384);       // [qh][qg][lane][2] = 2KB
    if (kh == 1) {
#pragma unroll
        for (int qg = 0; qg < 2; ++qg) {
            float2 v0; v0.x = m_r[qg]; v0.y = ls[qg];
            *reinterpret_cast<float2*>(mlb + (((qh * 2 + qg) * 64 + lane) * 2)) = v0;
        }
#pragma unroll
        for (int dg = 0; dg < 4; ++dg)
#pragma unroll
            for (int qg = 0; qg < 2; ++qg)
                *reinterpret_cast<f32x4*>(
                    mg + ((qh * 8 + dg * 2 + qg) * 64 + lane) * 4) = acc[dg][qg];
    }
    __syncthreads();
    if (kh == 0) {
        float sc0[2], sc1[2], rl[2];
#pragma unroll
        for (int qg = 0; qg < 2; ++qg) {
            const float2 v = *reinterpret_cast<const float2*>(
                mlb + (((qh * 2 + qg) * 64 + lane) * 2));
            const float mm = fmaxf(m_r[qg], v.x);
            sc0[qg] = exp2f(fmaxf(m_r[qg] - mm, -128.f));
            sc1[qg] = exp2f(fmaxf(v.x - mm, -128.f));
            rl[qg] = 1.0f / (ls[qg] * sc0[qg] + v.y * sc1[qg]);
        }
#pragma unroll
        for (int dg = 0; dg < 4; ++dg) {
#pragma unroll
            for (int qg = 0; qg < 2; ++qg) {
                const f32x4 o1 = *reinterpret_cast<const f32x4*>(
                    mg + ((qh * 8 + dg * 2 + qg) * 64 + lane) * 4);
                const f32x4 of = (acc[dg][qg] * sc0[qg] + o1 * sc1[qg]) * rl[qg];
                float* op = out + (size_t)(q0 + qg * 16 + lr) * HID
                          + h * HDIM + dg * 16 + hi * 4;
                *reinterpret_cast<f32x4*>(op) = of;
            }
        }
    }
}

// ---------------------------------------------------------------------------
extern "C" void kernel_launch(void* const* d_in, const int* in_sizes, int n_in,
                              void* d_out, int out_size, void* d_ws, size_t ws_size,
                              hipStream_t stream) {
    const float* hs   = (const float*)d_in[0];
    const float* mask = (const float*)d_in[1];
    const float* Wq   = (const float*)d_in[2];
    const float* bq   = (const float*)d_in[3];
    const float* Wk   = (const float*)d_in[4];
    const float* bk   = (const float*)d_in[5];
    const float* Wv   = (const float*)d_in[6];
    const float* bv   = (const float*)d_in[7];

    short* Qb = (short*)d_ws;                       // bf16 [SEQ][HID], pre-scaled
    short* Kb = Qb + (size_t)SEQ * HID;             // bf16 [SEQ][HID]
    short* Vt = Kb + (size_t)SEQ * HID;             // bf16 [HID][SEQ]
    float* out = (float*)d_out;

    // bf16 scratch carved from d_out (attn overwrites it at the very end)
    short* hsb = (short*)d_out;
    short* Wb  = hsb + (size_t)SEQ * HID;

    cast_bf16_kernel<<<dim3(SEQ * HID / 2048), 256, 0, stream>>>(hs, hsb);
    cast_w_kernel<<<dim3(HID * HID / 2048, 3), 256, 0, stream>>>(Wq, Wk, Wv, Wb);

    qkv_proj_kernel<<<dim3(HID / 128, SEQ / 128, 3), 256, 0, stream>>>(
        hsb, Wb, bq, bk, bv, Qb, Kb, Vt);

    attn_kernel<<<dim3(SEQ / KVB, NHEAD), 256, 0, stream>>>(Qb, Kb, Vt, mask, out);
}